// Round 4
// baseline (360.453 us; speedup 1.0000x reference)
//
#include <hip/hip_runtime.h>

#define N_NODES 100000
#define D_SRC 128
#define D_OUT 256
#define K_DIM 256   // D_DST + D_SRC
#define CAP 32      // bucket capacity per node (Poisson(6): P(deg>32) ~ 1e-15)
#define OVF_CAP 2048

typedef __attribute__((ext_vector_type(8))) short short8;
typedef __attribute__((ext_vector_type(4))) float float4v;

__device__ inline unsigned short f2bf(float f) {
    unsigned int u = __float_as_uint(f);
    u += 0x7FFF + ((u >> 16) & 1);   // round-to-nearest-even
    return (unsigned short)(u >> 16);
}

// ---------------------------------------------------------------------------
// Kernel 1: bucket edges by dst.
// ---------------------------------------------------------------------------
__global__ __launch_bounds__(256) void bucket_kernel(
    const int* __restrict__ ei,     // [2, E]
    int* __restrict__ deg,          // [N] (pre-zeroed)
    int* __restrict__ ovf_cnt,      // [1] (pre-zeroed)
    int* __restrict__ ovf,          // [OVF_CAP*2]
    int* __restrict__ bucket,       // [N*CAP]
    int n_edges)
{
    int e = blockIdx.x * 256 + threadIdx.x;
    if (e >= n_edges) return;
    int s = ei[e];
    int d = ei[n_edges + e];
    int pos = atomicAdd(deg + d, 1);
    if (pos < CAP) {
        bucket[(size_t)d * CAP + pos] = s;
    } else {
        int o = atomicAdd(ovf_cnt, 1);
        if (o < OVF_CAP) { ovf[2 * o] = s; ovf[2 * o + 1] = d; }
    }
}

// ---------------------------------------------------------------------------
// Kernel 2: gather-sum + mean + bf16 pack. One 64-lane wave per node.
// Writes aggb[node] = bf16( sum(x_src[srcs]) / max(deg,1) ) — no fp32 agg,
// no atomics. Overflow (deg>CAP) handled inline by scanning the tiny ovf
// list (never taken for this degree distribution, correct if it is).
// ---------------------------------------------------------------------------
__global__ __launch_bounds__(256) void gather_kernel(
    const float* __restrict__ x_src,    // [N, 128]
    const int*   __restrict__ deg,      // [N]
    const int*   __restrict__ bucket,   // [N*CAP]
    const int*   __restrict__ ovf_cnt,  // [1]
    const int*   __restrict__ ovf,      // [OVF_CAP*2]
    unsigned short* __restrict__ aggb)  // [N, 128] bf16 mean
{
    int node = blockIdx.x * 4 + (threadIdx.x >> 6);
    if (node >= N_NODES) return;
    int lane = threadIdx.x & 63;

    int dtot = deg[node];
    int n = (dtot < CAP) ? dtot : CAP;

    int idx = bucket[(size_t)node * CAP + (lane & 31)];

    float2 acc0 = make_float2(0.f, 0.f);
    float2 acc1 = make_float2(0.f, 0.f);
    int i = 0;
    for (; i + 2 <= n; i += 2) {
        int s0 = __shfl(idx, i);
        int s1 = __shfl(idx, i + 1);
        float2 v0 = *(const float2*)(x_src + (size_t)s0 * D_SRC + lane * 2);
        float2 v1 = *(const float2*)(x_src + (size_t)s1 * D_SRC + lane * 2);
        acc0.x += v0.x; acc0.y += v0.y;
        acc1.x += v1.x; acc1.y += v1.y;
    }
    if (i < n) {
        int s0 = __shfl(idx, i);
        float2 v0 = *(const float2*)(x_src + (size_t)s0 * D_SRC + lane * 2);
        acc0.x += v0.x; acc0.y += v0.y;
    }
    acc0.x += acc1.x; acc0.y += acc1.y;

    if (dtot > CAP) {   // astronomically rare; correctness fallback
        int oc = *ovf_cnt;
        if (oc > OVF_CAP) oc = OVF_CAP;
        for (int o = 0; o < oc; ++o) {
            if (ovf[2 * o + 1] == node) {
                int s0 = ovf[2 * o];
                float2 v0 = *(const float2*)(x_src + (size_t)s0 * D_SRC + lane * 2);
                acc0.x += v0.x; acc0.y += v0.y;
            }
        }
    }

    float inv = 1.0f / (float)((dtot > 1) ? dtot : 1);
    unsigned int packed = (unsigned int)f2bf(acc0.x * inv)
                        | ((unsigned int)f2bf(acc0.y * inv) << 16);
    ((unsigned int*)(aggb + (size_t)node * D_SRC))[lane] = packed;
}

// ---------------------------------------------------------------------------
// Kernel 3: W fp32 -> bf16 (once per launch, 65536 elements)
// ---------------------------------------------------------------------------
__global__ __launch_bounds__(256) void convert_w_kernel(
    const float* __restrict__ W, unsigned short* __restrict__ Wb)
{
    int i = blockIdx.x * 256 + threadIdx.x;   // 16384 float4s
    float4 v = ((const float4*)W)[i];
    ushort4 o;
    o.x = f2bf(v.x); o.y = f2bf(v.y); o.z = f2bf(v.z); o.w = f2bf(v.w);
    ((ushort4*)Wb)[i] = o;
}

// ---------------------------------------------------------------------------
// Kernel 4: LDS-free bf16-MFMA GEMM.
// out = relu([x_dst | aggb] @ Wb^T + b).  256 threads = 4 waves; each wave
// owns an independent 64x64 tile (rows shared across waves -> L1 reuse;
// Wb is L2-resident). Fragments loaded DIRECTLY from global as dwordx4:
// A[m][k]: m=lane&15, k=(lane>>4)*8..+7 (consecutive); same for B. No LDS,
// no barriers, no bank conflicts.
// ---------------------------------------------------------------------------
__global__ __launch_bounds__(256) void mfma_gemm_kernel(
    const float* __restrict__ x_dst,          // [N, 128] fp32
    const unsigned short* __restrict__ aggb,  // [N, 128] bf16 (mean)
    const unsigned short* __restrict__ Wb,    // [256, 256] bf16 [out][in]
    const float* __restrict__ bias,           // [256]
    float*       __restrict__ out)            // [N, 256] fp32
{
    int wave = threadIdx.x >> 6;  // 0..3 -> column block n0 = wave*64
    int lane = threadIdx.x & 63;
    int lrow = lane & 15;
    int kq   = lane >> 4;         // 0..3
    int m0 = blockIdx.x * 64;
    int n0 = wave * 64;

    float4v acc[4][4];
    #pragma unroll
    for (int i = 0; i < 4; ++i)
        #pragma unroll
        for (int j = 0; j < 4; ++j)
            acc[i][j] = (float4v){0.f, 0.f, 0.f, 0.f};

    int  rowv[4];
    bool rok[4];
    #pragma unroll
    for (int mf = 0; mf < 4; ++mf) {
        rowv[mf] = m0 + mf * 16 + lrow;
        rok[mf]  = rowv[mf] < N_NODES;
    }

    const short8 zfrag = (short8){0,0,0,0,0,0,0,0};

    #pragma unroll
    for (int kc = 0; kc < 8; ++kc) {
        const int k0 = kc * 32;
        short8 afrag[4], bfrag[4];

        if (kc < 4) {
            // A from x_dst (fp32 -> bf16 in-register)
            #pragma unroll
            for (int mf = 0; mf < 4; ++mf) {
                float4 v0 = make_float4(0.f, 0.f, 0.f, 0.f);
                float4 v1 = v0;
                if (rok[mf]) {
                    const float* p = x_dst + (size_t)rowv[mf] * D_SRC + k0 + kq * 8;
                    v0 = *(const float4*)p;
                    v1 = *(const float4*)(p + 4);
                }
                union { unsigned short s[8]; short8 v; } pk;
                pk.s[0] = f2bf(v0.x); pk.s[1] = f2bf(v0.y);
                pk.s[2] = f2bf(v0.z); pk.s[3] = f2bf(v0.w);
                pk.s[4] = f2bf(v1.x); pk.s[5] = f2bf(v1.y);
                pk.s[6] = f2bf(v1.z); pk.s[7] = f2bf(v1.w);
                afrag[mf] = pk.v;
            }
        } else {
            // A from aggb (bf16, one dwordx4)
            #pragma unroll
            for (int mf = 0; mf < 4; ++mf)
                afrag[mf] = rok[mf]
                    ? *(const short8*)(aggb + (size_t)rowv[mf] * D_SRC + (k0 - 128) + kq * 8)
                    : zfrag;
        }

        #pragma unroll
        for (int nf = 0; nf < 4; ++nf)
            bfrag[nf] = *(const short8*)(Wb + (size_t)(n0 + nf * 16 + lrow) * K_DIM + k0 + kq * 8);

        #pragma unroll
        for (int mf = 0; mf < 4; ++mf)
            #pragma unroll
            for (int nf = 0; nf < 4; ++nf)
                acc[mf][nf] = __builtin_amdgcn_mfma_f32_16x16x32_bf16(
                    afrag[mf], bfrag[nf], acc[mf][nf], 0, 0, 0);
    }

    // ---- epilogue: bias + relu + store (D layout: col=lane&15, row=kq*4+r) ----
    #pragma unroll
    for (int nf = 0; nf < 4; ++nf) {
        int col = n0 + nf * 16 + lrow;
        float bv = bias[col];
        #pragma unroll
        for (int mf = 0; mf < 4; ++mf) {
            int rbase = m0 + mf * 16 + kq * 4;
            #pragma unroll
            for (int r = 0; r < 4; ++r) {
                int row = rbase + r;
                if (row < N_NODES)
                    out[(size_t)row * D_OUT + col] = fmaxf(acc[mf][nf][r] + bv, 0.f);
            }
        }
    }
}

extern "C" void kernel_launch(void* const* d_in, const int* in_sizes, int n_in,
                              void* d_out, int out_size, void* d_ws, size_t ws_size,
                              hipStream_t stream) {
    const float* x_src = (const float*)d_in[0];
    const float* x_dst = (const float*)d_in[1];
    const int*   ei    = (const int*)d_in[2];
    const float* W     = (const float*)d_in[3];
    const float* bias  = (const float*)d_in[4];
    float* out = (float*)d_out;

    int n_edges = in_sizes[2] / 2;

    // workspace layout (all 16B-aligned):
    //   deg     : N_NODES int            (zeroed)
    //   ovf_cnt : 1 int + 3 pad          (zeroed)
    //   ovf     : OVF_CAP*2 int
    //   bucket  : N_NODES*CAP int
    //   aggb    : N_NODES*128 ushort (bf16 mean)
    //   Wb      : 256*256 ushort (bf16)
    int* deg     = (int*)d_ws;
    int* ovf_cnt = deg + N_NODES;
    int* ovf     = ovf_cnt + 4;
    int* bucket  = ovf + OVF_CAP * 2;
    unsigned short* aggb = (unsigned short*)(bucket + (size_t)N_NODES * CAP);
    unsigned short* Wb   = aggb + (size_t)N_NODES * D_SRC;

    hipMemsetAsync(d_ws, 0, (N_NODES + 4) * sizeof(int), stream);

    bucket_kernel<<<(n_edges + 255) / 256, 256, 0, stream>>>(
        ei, deg, ovf_cnt, ovf, bucket, n_edges);

    convert_w_kernel<<<(D_OUT * K_DIM / 4 + 255) / 256, 256, 0, stream>>>(W, Wb);

    gather_kernel<<<(N_NODES + 3) / 4, 256, 0, stream>>>(
        x_src, deg, bucket, ovf_cnt, ovf, aggb);

    mfma_gemm_kernel<<<(N_NODES + 63) / 64, 256, 0, stream>>>(
        x_dst, aggb, Wb, bias, out);
}

// Round 5
// 332.789 us; speedup vs baseline: 1.0831x; 1.0831x over previous
//
#include <hip/hip_runtime.h>

#define N_NODES 100000
#define D_SRC 128
#define D_OUT 256
#define K_DIM 256   // D_DST + D_SRC
#define CAP 32      // bucket capacity per node (Poisson(6): P(deg>32) ~ 1e-15)
#define OVF_CAP 2048

typedef __attribute__((ext_vector_type(8))) short short8;
typedef __attribute__((ext_vector_type(4))) float float4v;

__device__ inline unsigned short f2bf(float f) {
    unsigned int u = __float_as_uint(f);
    u += 0x7FFF + ((u >> 16) & 1);   // round-to-nearest-even
    return (unsigned short)(u >> 16);
}
__device__ inline float bf_lo(unsigned int u) { return __uint_as_float(u << 16); }
__device__ inline float bf_hi(unsigned int u) { return __uint_as_float(u & 0xFFFF0000u); }

// ---------------------------------------------------------------------------
// Kernel 1: bucket edges by dst.
// ---------------------------------------------------------------------------
__global__ __launch_bounds__(256) void bucket_kernel(
    const int* __restrict__ ei,     // [2, E]
    int* __restrict__ deg,          // [N] (pre-zeroed)
    int* __restrict__ ovf_cnt,      // [1] (pre-zeroed)
    int* __restrict__ ovf,          // [OVF_CAP*2]
    int* __restrict__ bucket,       // [N*CAP]
    int n_edges)
{
    int e = blockIdx.x * 256 + threadIdx.x;
    if (e >= n_edges) return;
    int s = ei[e];
    int d = ei[n_edges + e];
    int pos = atomicAdd(deg + d, 1);
    if (pos < CAP) {
        bucket[(size_t)d * CAP + pos] = s;
    } else {
        int o = atomicAdd(ovf_cnt, 1);
        if (o < OVF_CAP) { ovf[2 * o] = s; ovf[2 * o + 1] = d; }
    }
}

// ---------------------------------------------------------------------------
// Kernel 2: x_src fp32 -> bf16 pack (halves gather's scattered read bytes)
// ---------------------------------------------------------------------------
__global__ __launch_bounds__(256) void pack_src_kernel(
    const float* __restrict__ x, unsigned short* __restrict__ xb)
{
    int i = blockIdx.x * 256 + threadIdx.x;   // one float4 each; grid covers exactly
    float4 v = ((const float4*)x)[i];
    ushort4 o;
    o.x = f2bf(v.x); o.y = f2bf(v.y); o.z = f2bf(v.z); o.w = f2bf(v.w);
    ((ushort4*)xb)[i] = o;
}

// ---------------------------------------------------------------------------
// Kernel 3: W fp32 -> bf16
// ---------------------------------------------------------------------------
__global__ __launch_bounds__(256) void convert_w_kernel(
    const float* __restrict__ W, unsigned short* __restrict__ Wb)
{
    int i = blockIdx.x * 256 + threadIdx.x;
    float4 v = ((const float4*)W)[i];
    ushort4 o;
    o.x = f2bf(v.x); o.y = f2bf(v.y); o.z = f2bf(v.z); o.w = f2bf(v.w);
    ((ushort4*)Wb)[i] = o;
}

// ---------------------------------------------------------------------------
// Kernel 4: gather-sum over bf16 rows + mean + bf16 pack. One wave per node;
// lane owns one dword (2 bf16 cols). fp32 accumulation. Unroll x4 for MLP.
// ---------------------------------------------------------------------------
__global__ __launch_bounds__(256) void gather_kernel(
    const unsigned short* __restrict__ xsb,  // [N, 128] bf16
    const int*   __restrict__ deg,      // [N]
    const int*   __restrict__ bucket,   // [N*CAP]
    const int*   __restrict__ ovf_cnt,  // [1]
    const int*   __restrict__ ovf,      // [OVF_CAP*2]
    unsigned short* __restrict__ aggb)  // [N, 128] bf16 mean
{
    int node = blockIdx.x * 4 + (threadIdx.x >> 6);
    if (node >= N_NODES) return;
    int lane = threadIdx.x & 63;

    int dtot = deg[node];
    int n = (dtot < CAP) ? dtot : CAP;

    int idx = bucket[(size_t)node * CAP + (lane & 31)];

    float ax = 0.f, ay = 0.f;
    int i = 0;
    for (; i + 4 <= n; i += 4) {
        int s0 = __shfl(idx, i);
        int s1 = __shfl(idx, i + 1);
        int s2 = __shfl(idx, i + 2);
        int s3 = __shfl(idx, i + 3);
        unsigned int u0 = ((const unsigned int*)(xsb + (size_t)s0 * D_SRC))[lane];
        unsigned int u1 = ((const unsigned int*)(xsb + (size_t)s1 * D_SRC))[lane];
        unsigned int u2 = ((const unsigned int*)(xsb + (size_t)s2 * D_SRC))[lane];
        unsigned int u3 = ((const unsigned int*)(xsb + (size_t)s3 * D_SRC))[lane];
        ax += bf_lo(u0) + bf_lo(u1) + bf_lo(u2) + bf_lo(u3);
        ay += bf_hi(u0) + bf_hi(u1) + bf_hi(u2) + bf_hi(u3);
    }
    for (; i < n; ++i) {
        int s0 = __shfl(idx, i);
        unsigned int u0 = ((const unsigned int*)(xsb + (size_t)s0 * D_SRC))[lane];
        ax += bf_lo(u0);
        ay += bf_hi(u0);
    }

    if (dtot > CAP) {   // astronomically rare; correctness fallback
        int oc = *ovf_cnt;
        if (oc > OVF_CAP) oc = OVF_CAP;
        for (int o = 0; o < oc; ++o) {
            if (ovf[2 * o + 1] == node) {
                int s0 = ovf[2 * o];
                unsigned int u0 = ((const unsigned int*)(xsb + (size_t)s0 * D_SRC))[lane];
                ax += bf_lo(u0);
                ay += bf_hi(u0);
            }
        }
    }

    float inv = 1.0f / (float)((dtot > 1) ? dtot : 1);
    unsigned int packed = (unsigned int)f2bf(ax * inv)
                        | ((unsigned int)f2bf(ay * inv) << 16);
    ((unsigned int*)(aggb + (size_t)node * D_SRC))[lane] = packed;
}

// ---------------------------------------------------------------------------
// Kernel 5: LDS-free bf16-MFMA GEMM main loop (unchanged from round 4) +
// LDS-routed epilogue: per-wave 16x68 fp32 slice -> 256B-contiguous stores.
// ---------------------------------------------------------------------------
__global__ __launch_bounds__(256) void mfma_gemm_kernel(
    const float* __restrict__ x_dst,          // [N, 128] fp32
    const unsigned short* __restrict__ aggb,  // [N, 128] bf16 (mean)
    const unsigned short* __restrict__ Wb,    // [256, 256] bf16 [out][in]
    const float* __restrict__ bias,           // [256]
    float*       __restrict__ out)            // [N, 256] fp32
{
    __shared__ float eps[4][16][68];   // [wave][row][col64 + pad4]

    int wave = threadIdx.x >> 6;  // 0..3 -> column block n0 = wave*64
    int lane = threadIdx.x & 63;
    int lrow = lane & 15;
    int kq   = lane >> 4;         // 0..3
    int m0 = blockIdx.x * 64;
    int n0 = wave * 64;

    float4v acc[4][4];
    #pragma unroll
    for (int i = 0; i < 4; ++i)
        #pragma unroll
        for (int j = 0; j < 4; ++j)
            acc[i][j] = (float4v){0.f, 0.f, 0.f, 0.f};

    int  rowv[4];
    bool rok[4];
    #pragma unroll
    for (int mf = 0; mf < 4; ++mf) {
        rowv[mf] = m0 + mf * 16 + lrow;
        rok[mf]  = rowv[mf] < N_NODES;
    }

    const short8 zfrag = (short8){0,0,0,0,0,0,0,0};

    #pragma unroll
    for (int kc = 0; kc < 8; ++kc) {
        const int k0 = kc * 32;
        short8 afrag[4], bfrag[4];

        if (kc < 4) {
            // A from x_dst (fp32 -> bf16 in-register)
            #pragma unroll
            for (int mf = 0; mf < 4; ++mf) {
                float4 v0 = make_float4(0.f, 0.f, 0.f, 0.f);
                float4 v1 = v0;
                if (rok[mf]) {
                    const float* p = x_dst + (size_t)rowv[mf] * D_SRC + k0 + kq * 8;
                    v0 = *(const float4*)p;
                    v1 = *(const float4*)(p + 4);
                }
                union { unsigned short s[8]; short8 v; } pk;
                pk.s[0] = f2bf(v0.x); pk.s[1] = f2bf(v0.y);
                pk.s[2] = f2bf(v0.z); pk.s[3] = f2bf(v0.w);
                pk.s[4] = f2bf(v1.x); pk.s[5] = f2bf(v1.y);
                pk.s[6] = f2bf(v1.z); pk.s[7] = f2bf(v1.w);
                afrag[mf] = pk.v;
            }
        } else {
            // A from aggb (bf16, one dwordx4)
            #pragma unroll
            for (int mf = 0; mf < 4; ++mf)
                afrag[mf] = rok[mf]
                    ? *(const short8*)(aggb + (size_t)rowv[mf] * D_SRC + (k0 - 128) + kq * 8)
                    : zfrag;
        }

        #pragma unroll
        for (int nf = 0; nf < 4; ++nf)
            bfrag[nf] = *(const short8*)(Wb + (size_t)(n0 + nf * 16 + lrow) * K_DIM + k0 + kq * 8);

        #pragma unroll
        for (int mf = 0; mf < 4; ++mf)
            #pragma unroll
            for (int nf = 0; nf < 4; ++nf)
                acc[mf][nf] = __builtin_amdgcn_mfma_f32_16x16x32_bf16(
                    afrag[mf], bfrag[nf], acc[mf][nf], 0, 0, 0);
    }

    // ---- epilogue via LDS: bias+relu at write, coalesced 256B stores ----
    float bv[4];
    #pragma unroll
    for (int nf = 0; nf < 4; ++nf)
        bv[nf] = bias[n0 + nf * 16 + lrow];

    int srow   = lane >> 4;     // 0..3
    int schunk = lane & 15;     // 16B units across 64 cols

    #pragma unroll
    for (int mf = 0; mf < 4; ++mf) {
        // write slice: C[mf*16 + kq*4 + r][nf*16 + lrow]
        #pragma unroll
        for (int nf = 0; nf < 4; ++nf)
            #pragma unroll
            for (int r = 0; r < 4; ++r)
                eps[wave][kq * 4 + r][nf * 16 + lrow] =
                    fmaxf(acc[mf][nf][r] + bv[nf], 0.f);
        __syncthreads();
        // read back + store: 16 lanes cover 64 cols (256B contiguous), 4 rows/instr
        #pragma unroll
        for (int c = 0; c < 4; ++c) {
            int row  = c * 4 + srow;
            float4 v = *(const float4*)&eps[wave][row][schunk * 4];
            int grow = m0 + mf * 16 + row;
            if (grow < N_NODES)
                *(float4*)(out + (size_t)grow * D_OUT + n0 + schunk * 4) = v;
        }
        __syncthreads();
    }
}

extern "C" void kernel_launch(void* const* d_in, const int* in_sizes, int n_in,
                              void* d_out, int out_size, void* d_ws, size_t ws_size,
                              hipStream_t stream) {
    const float* x_src = (const float*)d_in[0];
    const float* x_dst = (const float*)d_in[1];
    const int*   ei    = (const int*)d_in[2];
    const float* W     = (const float*)d_in[3];
    const float* bias  = (const float*)d_in[4];
    float* out = (float*)d_out;

    int n_edges = in_sizes[2] / 2;

    // workspace layout (all 16B-aligned):
    //   deg     : N_NODES int            (zeroed)
    //   ovf_cnt : 1 int + 3 pad          (zeroed)
    //   ovf     : OVF_CAP*2 int
    //   bucket  : N_NODES*CAP int
    //   aggb    : N_NODES*128 ushort (bf16 mean)
    //   Wb      : 256*256 ushort (bf16)
    //   xsb     : N_NODES*128 ushort (bf16 x_src)
    int* deg     = (int*)d_ws;
    int* ovf_cnt = deg + N_NODES;
    int* ovf     = ovf_cnt + 4;
    int* bucket  = ovf + OVF_CAP * 2;
    unsigned short* aggb = (unsigned short*)(bucket + (size_t)N_NODES * CAP);
    unsigned short* Wb   = aggb + (size_t)N_NODES * D_SRC;
    unsigned short* xsb  = Wb + (size_t)D_OUT * K_DIM;

    hipMemsetAsync(d_ws, 0, (N_NODES + 4) * sizeof(int), stream);

    bucket_kernel<<<(n_edges + 255) / 256, 256, 0, stream>>>(
        ei, deg, ovf_cnt, ovf, bucket, n_edges);

    pack_src_kernel<<<(N_NODES * D_SRC / 4) / 256, 256, 0, stream>>>(x_src, xsb);

    convert_w_kernel<<<(D_OUT * K_DIM / 4) / 256, 256, 0, stream>>>(W, Wb);

    gather_kernel<<<(N_NODES + 3) / 4, 256, 0, stream>>>(
        xsb, deg, bucket, ovf_cnt, ovf, aggb);

    mfma_gemm_kernel<<<(N_NODES + 63) / 64, 256, 0, stream>>>(
        x_dst, aggb, Wb, bias, out);
}